// Round 8
// baseline (290.533 us; speedup 1.0000x reference)
//
#include <hip/hip_runtime.h>
#include <hip/hip_bf16.h>

#define NN 50000
#define NE 400000
#define AVG_LOG_F 2.1972245773362196f
#define EPSV 1e-5f

typedef __hip_bfloat16 bf16;
typedef __attribute__((ext_vector_type(8))) short short8v;
typedef __attribute__((ext_vector_type(4))) float f32x4;
typedef __attribute__((ext_vector_type(2))) _Float16 h2v;

__device__ __forceinline__ float b2f(bf16 v){ return __bfloat162float(v); }
__device__ __forceinline__ bf16  f2b(float v){ return __float2bfloat16(v); }
__device__ __forceinline__ short f2s(float v){
  bf16 b = __float2bfloat16(v);
  short s; __builtin_memcpy(&s, &b, 2); return s;
}
__device__ __forceinline__ float s2f(short v){
  bf16 b; __builtin_memcpy(&b, &v, 2); return __bfloat162float(b);
}

// ---------- h0b[n][d] = bf16( sum_c atom_emb[c][x[n][c]][d] ) ----------
__global__ void k_h0(const int* __restrict__ x, const float* __restrict__ aemb,
                     bf16* __restrict__ h0b){
  int idx = blockIdx.x * 256 + threadIdx.x;
  if (idx >= NN * 64) return;
  int n = idx >> 6, d = idx & 63;
  float acc = 0.f;
  #pragma unroll
  for (int c = 0; c < 9; ++c){
    int a = x[n * 9 + c];
    acc += aemb[(c * 64 + a) * 64 + d];
  }
  h0b[idx] = f2b(acc);
}

// ---------- degree histogram + bond code ----------
__global__ void k_deg_code(const int* __restrict__ ei, const int* __restrict__ ea,
                           int* __restrict__ deg, int* __restrict__ code){
  int e = blockIdx.x * 256 + threadIdx.x;
  if (e >= NE) return;
  int dst = ei[NE + e];
  atomicAdd(&deg[dst], 1);
  code[e] = ea[e * 3] + 8 * ea[e * 3 + 1] + 64 * ea[e * 3 + 2];
}

// ---------- exclusive scan of deg -> rowptr ----------
__global__ void k_scan1(const int* __restrict__ deg, int* __restrict__ rowptr,
                        int* __restrict__ part){
  __shared__ int s[256];
  int t = threadIdx.x, i = blockIdx.x * 256 + t;
  int v = (i < NN) ? deg[i] : 0;
  s[t] = v; __syncthreads();
  for (int off = 1; off < 256; off <<= 1){
    int xv = (t >= off) ? s[t - off] : 0;
    __syncthreads();
    s[t] += xv;
    __syncthreads();
  }
  if (i < NN) rowptr[i] = s[t] - v;
  if (t == 255) part[blockIdx.x] = s[255];
}

__global__ void k_scan2(int* __restrict__ part, int nblk){
  __shared__ int s[256];
  int t = threadIdx.x;
  int v = (t < nblk) ? part[t] : 0;
  s[t] = v; __syncthreads();
  for (int off = 1; off < 256; off <<= 1){
    int xv = (t >= off) ? s[t - off] : 0;
    __syncthreads();
    s[t] += xv;
    __syncthreads();
  }
  if (t < nblk) part[t] = s[t] - v;
}

__global__ void k_scan3(int* __restrict__ rowptr, const int* __restrict__ part,
                        const int* __restrict__ deg, float* __restrict__ amp,
                        float* __restrict__ att){
  int i = blockIdx.x * 256 + threadIdx.x;
  if (i < NN){
    rowptr[i] += part[blockIdx.x];
    int d = deg[i];
    float ld = logf((float)max(d, 1) + 1.0f);
    amp[i] = ld / AVG_LOG_F;
    att[i] = AVG_LOG_F / ld;
  }
  if (i == 0) rowptr[NN] = NE;
}

// ---------- scatter edges into CSR order, packed (src, code) ----------
__global__ void k_scatter(const int* __restrict__ ei, const int* __restrict__ code,
                          const int* __restrict__ rowptr, int* __restrict__ cursor,
                          int2* __restrict__ sedge){
  int e = blockIdx.x * 256 + threadIdx.x;
  if (e >= NE) return;
  int dst = ei[NE + e];
  int pos = rowptr[dst] + atomicAdd(&cursor[dst], 1);
  int2 v; v.x = ei[e]; v.y = code[e];
  sedge[pos] = v;
}

// ---------- packed C table (fp16): CTp[(code*64+d)*8 + l] ----------
__global__ void k_ctab(const float* __restrict__ bemb, const float* __restrict__ preW,
                       _Float16* __restrict__ CTp){
  __shared__ float et[64];
  int cb = blockIdx.x, l = blockIdx.y, t = threadIdx.x;
  int a0 = cb & 7, a1 = (cb >> 3) & 7, a2 = (cb >> 6) & 7;
  et[t] = bemb[(0 * 8 + a0) * 64 + t] + bemb[(1 * 8 + a1) * 64 + t] + bemb[(2 * 8 + a2) * 64 + t];
  __syncthreads();
  float acc = 0.f;
  const float* W = preW + (l * 192 + 128) * 64;
  for (int k = 0; k < 64; ++k) acc += et[k] * W[k * 64 + t];
  CTp[((size_t)cb * 64 + t) * 8 + l] = (_Float16)acc;
}

// ---------- Whsum / bias sums ----------
__global__ void k_whsum(const float* __restrict__ postW, const float* __restrict__ postb,
                        float* __restrict__ whs, float* __restrict__ bs){
  int idx = blockIdx.x * 256 + threadIdx.x;
  if (idx < 4096){
    int k = idx >> 6, d = idx & 63;
    float a = 0.f;
    for (int l = 0; l < 5; ++l) a += postW[(size_t)(l * 832 + 768 + k) * 64 + d];
    whs[idx] = a;
  }
  if (idx < 64){
    float a = 0.f;
    for (int l = 0; l < 5; ++l) a += postb[l * 64 + idx];
    bs[idx] = a;
  }
}

// ---------- WtK[g][c][l*256+k] = postW[l][g*256+k][c] (fragment-ready, K=1280) ----------
__global__ void k_wtk(const float* __restrict__ postW, bf16* __restrict__ WtK){
  int idx = blockIdx.x * 256 + threadIdx.x;
  if (idx >= 3 * 64 * 1280) return;
  int g = idx / (64 * 1280);
  int rem = idx % (64 * 1280);
  int c = rem / 1280;
  int kk = rem % 1280;
  int l = kk >> 8, k = kk & 255;
  WtK[idx] = f2b(postW[((size_t)l * 832 + g * 256 + k) * 64 + c]);
}

// ---------- Wtp896[gc][k] + bias896 ----------
__global__ void k_wtpre896(const float* __restrict__ preW, const float* __restrict__ preb,
                           const float* __restrict__ whs, const float* __restrict__ bs,
                           bf16* __restrict__ Wtp, float* __restrict__ bias896){
  int idx = blockIdx.x * 256 + threadIdx.x;
  if (idx < 896 * 64){
    int gc = idx >> 6, k = idx & 63;
    float v;
    if (gc < 320){
      int l = gc >> 6, c = gc & 63;
      v = preW[(size_t)(l * 192 + k) * 64 + c];
    } else if (gc < 832){
      int q = gc - 320, d = q >> 3, l = q & 7;
      v = (l < 5) ? preW[(size_t)(l * 192 + 64 + k) * 64 + d] : 0.f;
    } else {
      int c = gc - 832;
      v = whs[k * 64 + c] + ((k == c) ? 1.f : 0.f);
    }
    Wtp[idx] = f2b(v);
  }
  if (idx < 896){
    float b;
    if (idx < 320)      b = preb[(idx >> 6) * 64 + (idx & 63)];
    else if (idx < 832) b = 0.f;
    else                b = bs[idx - 832];
    bias896[idx] = b;
  }
}

// ---------- ABU(fp16)+out = h0b[N,64] @ Wtp896[64,896] via MFMA ----------
__global__ __launch_bounds__(256) void k_ab_mfma(const bf16* __restrict__ h0b,
                                                 const bf16* __restrict__ Wtp,
                                                 const float* __restrict__ bias896,
                                                 _Float16* __restrict__ ABU,
                                                 float* __restrict__ out){
  __shared__ bf16 As[128][72];
  __shared__ bf16 Bs[128][72];
  const int t = threadIdx.x;
  const int n0 = blockIdx.x * 128;
  const int gc0 = blockIdx.y * 128;
  const int lane = t & 63, wid = t >> 6;
  const int rw = wid * 32;
  const short* H  = (const short*)h0b;
  const short* Wp = (const short*)Wtp;

  #pragma unroll
  for (int i = 0; i < 4; ++i){
    int idx = t + i * 256;
    int r = idx >> 3, ko = (idx & 7) * 8;
    int n = n0 + r;
    short8v v = short8v{0,0,0,0,0,0,0,0};
    if (n < NN) v = *(const short8v*)(H + (size_t)n * 64 + ko);
    *(short8v*)&As[r][ko] = v;
  }
  #pragma unroll
  for (int i = 0; i < 4; ++i){
    int idx = t + i * 256;
    int cc = idx >> 3, ko = (idx & 7) * 8;
    *(short8v*)&Bs[cc][ko] = *(const short8v*)(Wp + (size_t)(gc0 + cc) * 64 + ko);
  }
  __syncthreads();

  f32x4 acc[2][8] = {};
  #pragma unroll
  for (int kk = 0; kk < 2; ++kk){
    short8v af0 = *(const short8v*)&As[rw + (lane & 15)][kk * 32 + (lane >> 4) * 8];
    short8v af1 = *(const short8v*)&As[rw + 16 + (lane & 15)][kk * 32 + (lane >> 4) * 8];
    #pragma unroll
    for (int j = 0; j < 8; ++j){
      short8v bfj = *(const short8v*)&Bs[j * 16 + (lane & 15)][kk * 32 + (lane >> 4) * 8];
      acc[0][j] = __builtin_amdgcn_mfma_f32_16x16x32_bf16(af0, bfj, acc[0][j], 0, 0, 0);
      acc[1][j] = __builtin_amdgcn_mfma_f32_16x16x32_bf16(af1, bfj, acc[1][j], 0, 0, 0);
    }
  }

  #pragma unroll
  for (int i = 0; i < 2; ++i){
    #pragma unroll
    for (int r = 0; r < 4; ++r){
      int n = n0 + rw + i * 16 + (lane >> 4) * 4 + r;
      if (n >= NN) continue;
      #pragma unroll
      for (int j = 0; j < 8; ++j){
        int gc = gc0 + j * 16 + (lane & 15);
        float v = acc[i][j][r] + bias896[gc];
        if (gc < 832) ABU[(size_t)n * 832 + gc] = (_Float16)v;
        else          out[(size_t)n * 64 + (gc - 832)] = v;
      }
    }
  }
}

// ---------- gather: one node per wave, fp16 packed stats, batch-4 ----------
// AGG[n][l*256 + a*64 + d] bf16, a in {mean,max,min,std}
__global__ __launch_bounds__(256) void k_gather(const _Float16* __restrict__ ABU,
                                                const _Float16* __restrict__ CTp,
                                                const int* __restrict__ rowptr,
                                                const int2* __restrict__ sedge,
                                                bf16* __restrict__ AGG){
  const int t = threadIdx.x, lane = t & 63, wid = t >> 6;
  const int n = blockIdx.x * 4 + wid;          // NN % 4 == 0, always valid
  const short* ABUs = (const short*)ABU;
  const short* CTps = (const short*)CTp;
  short* AGs = (short*)AGG;

  int r0 = rowptr[n], r1 = rowptr[n + 1];
  float s[5]  = {0.f, 0.f, 0.f, 0.f, 0.f};
  float sq[5] = {0.f, 0.f, 0.f, 0.f, 0.f};
  const _Float16 FLO = (_Float16)(-65504.f);
  const _Float16 FHI = (_Float16)( 65504.f);
  h2v mx01 = h2v{FLO, FLO}, mx23 = h2v{FLO, FLO}, mx45 = h2v{FLO, FLO};
  h2v mn01 = h2v{FHI, FHI}, mn23 = h2v{FHI, FHI}, mn45 = h2v{FHI, FHI};

  union P8 { short8v s; h2v h[4]; };

  for (int j = r0; j < r1; j += 4){
    int rem = r1 - j;
    int2 e0 = sedge[j];
    int2 e1 = (rem > 1) ? sedge[j + 1] : e0;
    int2 e2 = (rem > 2) ? sedge[j + 2] : e0;
    int2 e3 = (rem > 3) ? sedge[j + 3] : e0;
    P8 a0, c0, a1, c1, a2, c2, a3, c3;
    a0.s = *(const short8v*)(ABUs + (size_t)e0.x * 832 + 320 + lane * 8);
    c0.s = *(const short8v*)(CTps + (size_t)e0.y * 512 + lane * 8);
    a1.s = *(const short8v*)(ABUs + (size_t)e1.x * 832 + 320 + lane * 8);
    c1.s = *(const short8v*)(CTps + (size_t)e1.y * 512 + lane * 8);
    a2.s = *(const short8v*)(ABUs + (size_t)e2.x * 832 + 320 + lane * 8);
    c2.s = *(const short8v*)(CTps + (size_t)e2.y * 512 + lane * 8);
    a3.s = *(const short8v*)(ABUs + (size_t)e3.x * 832 + 320 + lane * 8);
    c3.s = *(const short8v*)(CTps + (size_t)e3.y * 512 + lane * 8);

    #define EDGE_ACC(A, C) {                                        \
      h2v t01 = A.h[0] + C.h[0];                                    \
      h2v t23 = A.h[1] + C.h[1];                                    \
      h2v t45 = A.h[2] + C.h[2];                                    \
      mx01 = __builtin_elementwise_max(mx01, t01);                  \
      mx23 = __builtin_elementwise_max(mx23, t23);                  \
      mx45 = __builtin_elementwise_max(mx45, t45);                  \
      mn01 = __builtin_elementwise_min(mn01, t01);                  \
      mn23 = __builtin_elementwise_min(mn23, t23);                  \
      mn45 = __builtin_elementwise_min(mn45, t45);                  \
      float f0 = (float)t01[0], f1 = (float)t01[1];                 \
      float f2 = (float)t23[0], f3 = (float)t23[1];                 \
      float f4 = (float)t45[0];                                     \
      s[0] += f0; sq[0] = fmaf(f0, f0, sq[0]);                      \
      s[1] += f1; sq[1] = fmaf(f1, f1, sq[1]);                      \
      s[2] += f2; sq[2] = fmaf(f2, f2, sq[2]);                      \
      s[3] += f3; sq[3] = fmaf(f3, f3, sq[3]);                      \
      s[4] += f4; sq[4] = fmaf(f4, f4, sq[4]);                      \
    }
    EDGE_ACC(a0, c0);
    if (rem > 1) EDGE_ACC(a1, c1);
    if (rem > 2) EDGE_ACC(a2, c2);
    if (rem > 3) EDGE_ACC(a3, c3);
    #undef EDGE_ACC
  }

  float mx[5] = {(float)mx01[0], (float)mx01[1], (float)mx23[0], (float)mx23[1], (float)mx45[0]};
  float mn[5] = {(float)mn01[0], (float)mn01[1], (float)mn23[0], (float)mn23[1], (float)mn45[0]};

  int d = r1 - r0;
  float degc = (float)((d > 0) ? d : 1);
  size_t base = (size_t)n * 1280;
  #pragma unroll
  for (int l = 0; l < 5; ++l){
    float K = (float)ABU[(size_t)n * 832 + l * 64 + lane];   // includes pre_b
    float mean = ((float)d * K + s[l]) / degc;
    float MX = (d > 0) ? (K + mx[l]) : 0.f;
    float MN = (d > 0) ? (K + mn[l]) : 0.f;
    float mu = s[l] / degc;
    float var = fmaxf(sq[l] / degc - mu * mu, 0.f);
    float sd = sqrtf(var + EPSV);
    AGs[base + l * 256 + lane]       = f2s(mean);
    AGs[base + l * 256 + 64 + lane]  = f2s(MX);
    AGs[base + l * 256 + 128 + lane] = f2s(MN);
    AGs[base + l * 256 + 192 + lane] = f2s(sd);
  }
}

// ---------- posttrans GEMM: out += AGG[N,1280] @ WtK[1280,192] with amp/att combine ----------
// 512 thr = 8 waves: 2 row-halves x 4 col-triples; 128 rows/block; BK=128 double-buffered
__global__ __launch_bounds__(512) void k_post5(const bf16* __restrict__ AGG,
                                               const bf16* __restrict__ WtK,
                                               const float* __restrict__ amp,
                                               const float* __restrict__ att,
                                               float* __restrict__ out){
  __shared__ short As[2][128][140];   // stride 140 shorts = 70 dwords -> conflict-free b128
  const int t = threadIdx.x, lane = t & 63, wid = t >> 6;
  const int n0 = blockIdx.x * 128;
  const int w4 = wid & 3, rh = wid >> 2;
  const short* AGs = (const short*)AGG;
  const short* Ws  = (const short*)WtK;
  const short8v zv = short8v{0,0,0,0,0,0,0,0};

  // stage kt=0 into buf 0
  #pragma unroll
  for (int i = 0; i < 4; ++i){
    int id = t + i * 512;            // 0..2047: 128 rows x 16 chunks
    int r = id >> 4, ko = (id & 15) * 8;
    int n = n0 + r;
    short8v v = zv;
    if (n < NN) v = *(const short8v*)(AGs + (size_t)n * 1280 + ko);
    *(short8v*)&As[0][r][ko] = v;
  }
  __syncthreads();

  f32x4 acc[4][3] = {};
  for (int kt = 0; kt < 10; ++kt){
    const int cur = kt & 1;
    // prefetch next A-tile into registers
    short8v pref[4];
    if (kt < 9){
      #pragma unroll
      for (int i = 0; i < 4; ++i){
        int id = t + i * 512;
        int r = id >> 4, ko = (id & 15) * 8;
        int n = n0 + r;
        pref[i] = zv;
        if (n < NN) pref[i] = *(const short8v*)(AGs + (size_t)n * 1280 + (kt + 1) * 128 + ko);
      }
    }
    // MFMA cluster for current tile
    #pragma unroll
    for (int kk = 0; kk < 4; ++kk){
      short8v bfg[3];
      #pragma unroll
      for (int g = 0; g < 3; ++g)
        bfg[g] = *(const short8v*)(Ws + (size_t)(g * 64 + w4 * 16 + (lane & 15)) * 1280 +
                                   kt * 128 + kk * 32 + (lane >> 4) * 8);
      #pragma unroll
      for (int rf = 0; rf < 4; ++rf){
        short8v af = *(const short8v*)&As[cur][rh * 64 + rf * 16 + (lane & 15)]
                                         [kk * 32 + (lane >> 4) * 8];
        #pragma unroll
        for (int g = 0; g < 3; ++g)
          acc[rf][g] = __builtin_amdgcn_mfma_f32_16x16x32_bf16(af, bfg[g], acc[rf][g], 0, 0, 0);
      }
    }
    // write prefetched tile to the other buffer
    if (kt < 9){
      #pragma unroll
      for (int i = 0; i < 4; ++i){
        int id = t + i * 512;
        int r = id >> 4, ko = (id & 15) * 8;
        *(short8v*)&As[cur ^ 1][r][ko] = pref[i];
      }
    }
    __syncthreads();
  }

  // epilogue: out += U + amp*V + att*W
  #pragma unroll
  for (int rf = 0; rf < 4; ++rf){
    #pragma unroll
    for (int r = 0; r < 4; ++r){
      int n = n0 + rh * 64 + rf * 16 + (lane >> 4) * 4 + r;
      if (n >= NN) continue;
      float am = amp[n], at = att[n];
      int c = w4 * 16 + (lane & 15);
      out[(size_t)n * 64 + c] += acc[rf][0][r] + am * acc[rf][1][r] + at * acc[rf][2][r];
    }
  }
}

extern "C" void kernel_launch(void* const* d_in, const int* in_sizes, int n_in,
                              void* d_out, int out_size, void* d_ws, size_t ws_size,
                              hipStream_t stream){
  const int*   x     = (const int*)d_in[0];
  const int*   ei    = (const int*)d_in[1];
  const int*   ea    = (const int*)d_in[2];
  const float* aemb  = (const float*)d_in[3];
  const float* bemb  = (const float*)d_in[4];
  const float* preW  = (const float*)d_in[5];
  const float* preb  = (const float*)d_in[6];
  const float* postW = (const float*)d_in[7];
  const float* postb = (const float*)d_in[8];
  float* out = (float*)d_out;

  char* p = (char*)d_ws;
  auto alloc = [&](size_t bytes) -> char* {
    char* r = p;
    p += (bytes + 255) & ~(size_t)255;
    return r;
  };
  bf16*      h0b     = (bf16*)     alloc((size_t)NN * 64 * 2);
  _Float16*  ABU     = (_Float16*) alloc((size_t)NN * 832 * 2);
  bf16*      AGG     = (bf16*)     alloc((size_t)NN * 1280 * 2);
  int*       deg     = (int*)      alloc((size_t)NN * 4);
  int*       rowptr  = (int*)      alloc((size_t)(NN + 1) * 4);
  int*       cursor  = (int*)      alloc((size_t)NN * 4);
  float*     amp     = (float*)    alloc((size_t)NN * 4);
  float*     att     = (float*)    alloc((size_t)NN * 4);
  int*       code    = (int*)      alloc((size_t)NE * 4);
  int2*      sedge   = (int2*)     alloc((size_t)NE * 8);
  _Float16*  CTp     = (_Float16*) alloc((size_t)512 * 64 * 8 * 2 + 64);
  float*     whs     = (float*)    alloc((size_t)64 * 64 * 4);
  float*     bs      = (float*)    alloc((size_t)64 * 4);
  int*       part    = (int*)      alloc((size_t)256 * 4);
  bf16*      WtK     = (bf16*)     alloc((size_t)3 * 64 * 1280 * 2);
  bf16*      Wtp     = (bf16*)     alloc((size_t)896 * 64 * 2);
  float*     bias896 = (float*)    alloc((size_t)896 * 4);
  if ((size_t)(p - (char*)d_ws) > ws_size) return;

  hipMemsetAsync(deg, 0, (size_t)NN * 4, stream);
  hipMemsetAsync(cursor, 0, (size_t)NN * 4, stream);

  k_h0<<<dim3((NN * 64 + 255) / 256), 256, 0, stream>>>(x, aemb, h0b);
  k_deg_code<<<dim3((NE + 255) / 256), 256, 0, stream>>>(ei, ea, deg, code);
  int nblk = (NN + 255) / 256;
  k_scan1<<<dim3(nblk), 256, 0, stream>>>(deg, rowptr, part);
  k_scan2<<<dim3(1), 256, 0, stream>>>(part, nblk);
  k_scan3<<<dim3(nblk), 256, 0, stream>>>(rowptr, part, deg, amp, att);
  k_scatter<<<dim3((NE + 255) / 256), 256, 0, stream>>>(ei, code, rowptr, cursor, sedge);
  k_ctab<<<dim3(512, 5), 64, 0, stream>>>(bemb, preW, CTp);
  k_whsum<<<dim3(16), 256, 0, stream>>>(postW, postb, whs, bs);
  k_wtk<<<dim3((3 * 64 * 1280 + 255) / 256), 256, 0, stream>>>(postW, WtK);
  k_wtpre896<<<dim3((896 * 64 + 255) / 256), 256, 0, stream>>>(preW, preb, whs, bs,
                                                               Wtp, bias896);
  k_ab_mfma<<<dim3((NN + 127) / 128, 7), 256, 0, stream>>>(h0b, Wtp, bias896, ABU, out);
  k_gather<<<dim3(NN / 4), 256, 0, stream>>>(ABU, CTp, rowptr, sedge, AGG);
  k_post5<<<dim3((NN + 127) / 128), 512, 0, stream>>>(AGG, WtK, amp, att, out);
}